// Round 1
// baseline (531.191 us; speedup 1.0000x reference)
//
#include <hip/hip_runtime.h>
#include <stdint.h>

#define CDIM   4096
#define S_N    3355443
#define R_N    1048576
#define N1     (S_N + R_N)                 // 4404019 contributions
#define TILE   4096
#define NTILES ((N1 + TILE - 1) / TILE)    // 1076
#define NPAD   (NTILES * TILE)             // 4407296
#define NSB    (NPAD / 256)                // 17216 (one-elem-per-thread blocks)
#define PAD_KEY 0xFFFFFFu
#define PAD_VAL 0xFFFFFFFFu                // -NaN bits: impossible for real values

// Exclusive block-wide scan over 256 threads (4 waves). Returns exclusive
// prefix; *tot = block total. Uses lw[4] LDS scratch; contains syncthreads.
static __device__ __forceinline__ unsigned blockScanExcl(unsigned v, unsigned t,
                                                         unsigned* lw, unsigned* tot){
  unsigned lane = t & 63u, w = t >> 6;
  unsigned x = v;
  #pragma unroll
  for (int off = 1; off < 64; off <<= 1){
    unsigned y = __shfl_up(x, off, 64);
    if (lane >= (unsigned)off) x += y;
  }
  if (lane == 63u) lw[w] = x;
  __syncthreads();
  unsigned woff = 0;
  for (unsigned i = 0; i < w; i++) woff += lw[i];
  *tot = lw[0] + lw[1] + lw[2] + lw[3];
  __syncthreads();
  return x + woff - v;
}

// Build packed contribution array: high32 = key, low32 = value bits.
// Order: samples (pos 0..S-1), results (S..N1-1), padding -> stable sort
// preserves segment_sum's accumulation order exactly.
__global__ __launch_bounds__(256) void k_build(const int* __restrict__ sidx,
                                               const int* __restrict__ ridx,
                                               const float* __restrict__ rval,
                                               const float* __restrict__ grad,
                                               uint64_t* __restrict__ A){
  unsigned i = blockIdx.x * 256u + threadIdx.x;
  uint32_t key, vb;
  if (i < S_N){
    key = (uint32_t)sidx[i];
    vb  = __float_as_uint(fabsf(grad[i]));
  } else if (i < N1){
    unsigned j = i - S_N;
    key = (uint32_t)(ridx[2u*j] * CDIM + ridx[2u*j + 1u]);
    // bit-exact vs Python: double math, single rounding to fp32
    const float ADJF = (float)(1.0 - (3355443.0 / 16777216.0) * (1.0 - 0.95));
    vb = __float_as_uint(ADJF * rval[j]);
  } else {
    key = PAD_KEY; vb = PAD_VAL;   // sorts to end of key 0xFFFFFF segment; walk stops on PAD_VAL
  }
  A[i] = ((uint64_t)key << 32) | (uint64_t)vb;
}

// Per-tile 256-bin histogram of digit (e >> shift) & 0xFF. hist layout [digit][tile].
__global__ __launch_bounds__(256) void k_hist(const uint64_t* __restrict__ in, unsigned shift,
                                              unsigned* __restrict__ gh){
  __shared__ unsigned h[256];
  unsigned t = threadIdx.x;
  h[t] = 0; __syncthreads();
  size_t base = (size_t)blockIdx.x * TILE;
  #pragma unroll
  for (int r = 0; r < 16; r++){
    uint64_t e = in[base + (size_t)r*256 + t];
    atomicAdd(&h[(unsigned)((e >> shift) & 0xFF)], 1u);
  }
  __syncthreads();
  gh[t * NTILES + blockIdx.x] = h[t];
}

// Per-digit row scan: block d turns gh[d][*] into exclusive tile prefixes, writes digit total.
__global__ __launch_bounds__(256) void k_scanrows(unsigned* __restrict__ gh,
                                                  unsigned* __restrict__ dtot){
  __shared__ unsigned lw[4];
  unsigned d = blockIdx.x, t = threadIdx.x;
  unsigned carry = 0;
  for (unsigned base = 0; base < NTILES; base += 256){
    unsigned i = base + t;
    unsigned v = (i < NTILES) ? gh[d * NTILES + i] : 0u;
    unsigned tot;
    unsigned e = blockScanExcl(v, t, lw, &tot);
    if (i < NTILES) gh[d * NTILES + i] = e + carry;
    carry += tot;
  }
  if (t == 0) dtot[d] = carry;
}

// Stable radix scatter. Wave w owns contiguous chunk [w*1024, w*1024+1024) of the
// tile, processed striped (round r, lane) so rank order == memory order (stability).
__global__ __launch_bounds__(256) void k_scatter(const uint64_t* __restrict__ in,
                                                 uint64_t* __restrict__ out,
                                                 unsigned shift,
                                                 const unsigned* __restrict__ gh,
                                                 const unsigned* __restrict__ dtot){
  __shared__ unsigned wrun[4*256];
  __shared__ unsigned destB[4*256];
  __shared__ unsigned lw[4];
  unsigned t = threadIdx.x, lane = t & 63u, w = t >> 6;
  wrun[t] = 0; wrun[256+t] = 0; wrun[512+t] = 0; wrun[768+t] = 0;
  __syncthreads();
  uint64_t ltm = (lane == 0) ? 0ull : (~0ull >> (64u - lane));
  uint64_t elems[16]; unsigned rnk[16]; unsigned dg[16];
  size_t base = (size_t)blockIdx.x * TILE + (size_t)w * 1024;
  #pragma unroll
  for (int r = 0; r < 16; r++){
    uint64_t e = in[base + (size_t)r*64 + lane];
    elems[r] = e;
    unsigned d = (unsigned)((e >> shift) & 0xFF);
    uint64_t m = ~0ull;
    #pragma unroll
    for (int b = 0; b < 8; b++){
      uint64_t bb = __ballot((d >> b) & 1u);
      m &= ((d >> b) & 1u) ? bb : ~bb;
    }
    unsigned rr   = (unsigned)__popcll(m & ltm);      // rank among same digit, this round
    unsigned prev = wrun[w*256 + d];                  // wave-running count before this round
    __builtin_amdgcn_wave_barrier();
    if (rr == 0) wrun[w*256 + d] = prev + (unsigned)__popcll(m);  // leader updates
    __builtin_amdgcn_wave_barrier();
    rnk[r] = prev + rr;
    dg[r]  = d;
  }
  __syncthreads();
  { // per-digit global base = scan(dtot) + tile prefix + wave prefix
    unsigned d = t;
    unsigned total = dtot[d];
    unsigned tot;
    unsigned dbase = blockScanExcl(total, t, lw, &tot);
    unsigned b0 = dbase + gh[d * NTILES + blockIdx.x];
    unsigned acc = 0;
    #pragma unroll
    for (int ww = 0; ww < 4; ww++){ destB[ww*256 + d] = b0 + acc; acc += wrun[ww*256 + d]; }
  }
  __syncthreads();
  #pragma unroll
  for (int r = 0; r < 16; r++)
    out[ destB[w*256 + dg[r]] + rnk[r] ] = elems[r];
}

// Count segment heads (key change points) per 256-elem block.
__global__ __launch_bounds__(256) void k_headcount(const uint64_t* __restrict__ in,
                                                   unsigned* __restrict__ hcnt){
  __shared__ unsigned wc[4];
  unsigned t = threadIdx.x, lane = t & 63u, w = t >> 6;
  size_t p = (size_t)blockIdx.x * 256 + t;
  uint32_t k = (uint32_t)(in[p] >> 32);
  bool head = (p == 0) || ((uint32_t)(in[p-1] >> 32) != k);
  uint64_t m = __ballot(head);
  if (lane == 0) wc[w] = (unsigned)__popcll(m);
  __syncthreads();
  if (t == 0) hcnt[blockIdx.x] = wc[0] + wc[1] + wc[2] + wc[3];
}

// Single-block exclusive scan of the 17216 head counts (in place).
__global__ __launch_bounds__(256) void k_scanheads(unsigned* __restrict__ hcnt){
  __shared__ unsigned lw[4];
  unsigned t = threadIdx.x;
  unsigned carry = 0;
  for (unsigned base = 0; base < NSB; base += 256){
    unsigned i = base + t;
    unsigned v = (i < NSB) ? hcnt[i] : 0u;
    unsigned tot;
    unsigned e = blockScanExcl(v, t, lw, &tot);
    if (i < NSB) hcnt[i] = e + carry;
    carry += tot;
  }
}

// Sentinel-fill candidate array: sortkey 0xFFFFFFFF (value 0.0) sorts last.
__global__ __launch_bounds__(256) void k_prefill(uint64_t* __restrict__ A){
  size_t i = (size_t)blockIdx.x * 256 + threadIdx.x;
  A[i] = ((uint64_t)PAD_KEY << 32) | (uint64_t)PAD_VAL;
}

// In-order segmented sum: head thread walks its segment sequentially (original
// position order within key thanks to stable key sort), writes candidate
// (key<<32 | ~sum_bits) at its dense head rank -> candidates key-ascending.
__global__ __launch_bounds__(256) void k_segsum(const uint64_t* __restrict__ in,
                                                uint64_t* __restrict__ out,
                                                const unsigned* __restrict__ hbase){
  __shared__ unsigned wc[4], woffs[4];
  unsigned t = threadIdx.x, lane = t & 63u, w = t >> 6;
  size_t p = (size_t)blockIdx.x * 256 + t;
  uint64_t e0 = in[p];
  uint32_t k = (uint32_t)(e0 >> 32);
  bool head = (p == 0) || ((uint32_t)(in[p-1] >> 32) != k);
  uint64_t m = __ballot(head);
  if (lane == 0) wc[w] = (unsigned)__popcll(m);
  __syncthreads();
  if (t == 0){ unsigned a = 0; for (int i = 0; i < 4; i++){ woffs[i] = a; a += wc[i]; } }
  __syncthreads();
  if (head && (uint32_t)e0 != PAD_VAL){
    uint64_t ltm = (lane == 0) ? 0ull : (~0ull >> (64u - lane));
    unsigned rank = (unsigned)__popcll(m & ltm);
    unsigned oidx = hbase[blockIdx.x] + woffs[w] + rank;
    float s = __uint_as_float((uint32_t)e0);
    size_t q = p + 1;
    while (q < NPAD){
      uint64_t e = in[q];
      if ((uint32_t)(e >> 32) != k) break;
      uint32_t vb = (uint32_t)e;
      if (vb == PAD_VAL) break;        // stop at build padding
      s += __uint_as_float(vb);        // fp32, original order: matches segment_sum
      q++;
    }
    out[oidx] = ((uint64_t)k << 32) | (uint64_t)(uint32_t)(~__float_as_uint(s));
  }
}

// Emit top-R: indices as exact integer-valued floats, then values.
__global__ __launch_bounds__(256) void k_writeout(const uint64_t* __restrict__ A,
                                                  float* __restrict__ out){
  unsigned i = blockIdx.x * 256u + threadIdx.x;
  uint64_t e = A[i];
  uint32_t key = (uint32_t)(e >> 32);
  float val = __uint_as_float(~(uint32_t)e);
  out[2u*i]        = (float)(key >> 12);
  out[2u*i + 1u]   = (float)(key & 4095u);
  out[2u*R_N + i]  = val;
}

extern "C" void kernel_launch(void* const* d_in, const int* in_sizes, int n_in,
                              void* d_out, int out_size, void* d_ws, size_t ws_size,
                              hipStream_t stream) {
  const int*   sidx = (const int*)d_in[0];
  const int*   ridx = (const int*)d_in[1];
  const float* rval = (const float*)d_in[2];
  const float* grad = (const float*)d_in[3];
  float* out = (float*)d_out;

  uint64_t* A0   = (uint64_t*)d_ws;                       // 35.3 MB
  uint64_t* A1   = A0 + NPAD;                             // 35.3 MB
  unsigned* gh   = (unsigned*)(A1 + NPAD);                // 256*NTILES = 1.1 MB
  unsigned* dtot = gh + 256 * NTILES;                     // 1 KB
  unsigned* hcnt = dtot + 256;                            // 67 KB

  k_build<<<NSB, 256, 0, stream>>>(sidx, ridx, rval, grad, A0);

  // Stable key sort: 24 bits, 3 x 8-bit passes. A0->A1->A0->A1.
  k_hist    <<<NTILES, 256, 0, stream>>>(A0, 32, gh);
  k_scanrows<<<256,    256, 0, stream>>>(gh, dtot);
  k_scatter <<<NTILES, 256, 0, stream>>>(A0, A1, 32, gh, dtot);
  k_hist    <<<NTILES, 256, 0, stream>>>(A1, 40, gh);
  k_scanrows<<<256,    256, 0, stream>>>(gh, dtot);
  k_scatter <<<NTILES, 256, 0, stream>>>(A1, A0, 40, gh, dtot);
  k_hist    <<<NTILES, 256, 0, stream>>>(A0, 48, gh);
  k_scanrows<<<256,    256, 0, stream>>>(gh, dtot);
  k_scatter <<<NTILES, 256, 0, stream>>>(A0, A1, 48, gh, dtot);

  // Coalesce: heads, dense ranks, in-order segment sums into prefilled A0.
  k_headcount<<<NSB, 256, 0, stream>>>(A1, hcnt);
  k_scanheads<<<1,   256, 0, stream>>>(hcnt);
  k_prefill  <<<NSB, 256, 0, stream>>>(A0);
  k_segsum   <<<NSB, 256, 0, stream>>>(A1, A0, hcnt);

  // Stable value sort: 32 bits of ~vbits (descending value, stable => key-asc ties).
  // A0->A1->A0->A1->A0.
  k_hist    <<<NTILES, 256, 0, stream>>>(A0, 0, gh);
  k_scanrows<<<256,    256, 0, stream>>>(gh, dtot);
  k_scatter <<<NTILES, 256, 0, stream>>>(A0, A1, 0, gh, dtot);
  k_hist    <<<NTILES, 256, 0, stream>>>(A1, 8, gh);
  k_scanrows<<<256,    256, 0, stream>>>(gh, dtot);
  k_scatter <<<NTILES, 256, 0, stream>>>(A1, A0, 8, gh, dtot);
  k_hist    <<<NTILES, 256, 0, stream>>>(A0, 16, gh);
  k_scanrows<<<256,    256, 0, stream>>>(gh, dtot);
  k_scatter <<<NTILES, 256, 0, stream>>>(A0, A1, 16, gh, dtot);
  k_hist    <<<NTILES, 256, 0, stream>>>(A1, 24, gh);
  k_scanrows<<<256,    256, 0, stream>>>(gh, dtot);
  k_scatter <<<NTILES, 256, 0, stream>>>(A1, A0, 24, gh, dtot);

  k_writeout<<<R_N / 256, 256, 0, stream>>>(A0, out);
}

// Round 2
// 433.351 us; speedup vs baseline: 1.2258x; 1.2258x over previous
//
#include <hip/hip_runtime.h>
#include <stdint.h>

#define CDIM   4096
#define S_N    3355443
#define R_N    1048576
#define N1     (S_N + R_N)                 // 4404019 contributions
#define TILE   4096
#define NTILES ((N1 + TILE - 1) / TILE)    // 1076
#define NPAD   (NTILES * TILE)             // 4407296
#define NSB    (NPAD / 256)                // 17216
#define PAD_KEY 0xFFFFFFu
#define PAD_VAL 0xFFFFFFFFu                // impossible value bits (sums are >= +0)

// Exclusive block-wide scan over 256 threads (4 waves). Contains syncthreads.
static __device__ __forceinline__ unsigned blockScanExcl(unsigned v, unsigned t,
                                                         unsigned* lw, unsigned* tot){
  unsigned lane = t & 63u, w = t >> 6;
  unsigned x = v;
  #pragma unroll
  for (int off = 1; off < 64; off <<= 1){
    unsigned y = __shfl_up(x, off, 64);
    if (lane >= (unsigned)off) x += y;
  }
  if (lane == 63u) lw[w] = x;
  __syncthreads();
  unsigned woff = 0;
  for (unsigned i = 0; i < w; i++) woff += lw[i];
  *tot = lw[0] + lw[1] + lw[2] + lw[3];
  __syncthreads();
  return x + woff - v;
}

// Build packed contributions: high32 = key, low32 = value bits. Samples first,
// then decayed buffer entries, then padding -> stable sort preserves
// segment_sum's accumulation order exactly.
__global__ __launch_bounds__(256) void k_build(const int* __restrict__ sidx,
                                               const int* __restrict__ ridx,
                                               const float* __restrict__ rval,
                                               const float* __restrict__ grad,
                                               uint64_t* __restrict__ A){
  unsigned i = blockIdx.x * 256u + threadIdx.x;
  uint32_t key, vb;
  if (i < S_N){
    key = (uint32_t)sidx[i];
    vb  = __float_as_uint(fabsf(grad[i]));
  } else if (i < N1){
    unsigned j = i - S_N;
    key = (uint32_t)(ridx[2u*j] * CDIM + ridx[2u*j + 1u]);
    const float ADJF = (float)(1.0 - (3355443.0 / 16777216.0) * (1.0 - 0.95));
    vb = __float_as_uint(ADJF * rval[j]);
  } else {
    key = PAD_KEY; vb = PAD_VAL;
  }
  A[i] = ((uint64_t)key << 32) | (uint64_t)vb;
}

// Per-tile 256-bin histogram of digit (e >> shift) & 0xFF. Layout [digit][tile].
__global__ __launch_bounds__(256) void k_hist(const uint64_t* __restrict__ in, unsigned shift,
                                              unsigned* __restrict__ gh){
  __shared__ unsigned h[256];
  unsigned t = threadIdx.x;
  h[t] = 0; __syncthreads();
  size_t base = (size_t)blockIdx.x * TILE;
  #pragma unroll
  for (int r = 0; r < 16; r++){
    uint64_t e = in[base + (size_t)r*256 + t];
    atomicAdd(&h[(unsigned)((e >> shift) & 0xFF)], 1u);
  }
  __syncthreads();
  gh[t * NTILES + blockIdx.x] = h[t];
}

// Row scan: block d turns gh[d][*] into exclusive tile prefixes + digit total.
__global__ __launch_bounds__(256) void k_scanrows(unsigned* __restrict__ gh,
                                                  unsigned* __restrict__ dtot){
  __shared__ unsigned lw[4];
  unsigned d = blockIdx.x, t = threadIdx.x;
  unsigned carry = 0;
  for (unsigned base = 0; base < NTILES; base += 256){
    unsigned i = base + t;
    unsigned v = (i < NTILES) ? gh[d * NTILES + i] : 0u;
    unsigned tot;
    unsigned e = blockScanExcl(v, t, lw, &tot);
    if (i < NTILES) gh[d * NTILES + i] = e + carry;
    carry += tot;
  }
  if (t == 0) dtot[d] = carry;
}

// ---- LDS-staged stable radix scatter -------------------------------------
// Phase A: per-wave stable ranks (wave w owns chunk [w*1024, w*1024+1024),
// striped rounds so rank order == memory order).
// Phase B: block digit scan -> LDS layout bases + global put bases.
// Phase C: stage tile into LDS ordered by (digit, original pos).
// Phase D: linear sweep -> coalesced ~16-elem runs per digit to global.
template <bool FINAL>
__device__ __forceinline__ void scatter_body(const uint64_t* __restrict__ in,
                                             uint64_t* __restrict__ out,
                                             float* __restrict__ fout,
                                             unsigned shift,
                                             const unsigned* __restrict__ gh,
                                             const unsigned* __restrict__ dtot){
  __shared__ unsigned wrun[4*256];
  __shared__ unsigned gput[256];
  __shared__ unsigned lw[4];
  __shared__ uint64_t stage[TILE];       // 32 KB
  unsigned t = threadIdx.x, lane = t & 63u, w = t >> 6;
  wrun[t] = 0; wrun[256+t] = 0; wrun[512+t] = 0; wrun[768+t] = 0;
  __syncthreads();
  uint64_t ltm = (lane == 0) ? 0ull : (~0ull >> (64u - lane));
  uint64_t elems[16]; unsigned rnk[16]; unsigned dg[16];
  size_t base = (size_t)blockIdx.x * TILE + (size_t)w * 1024;
  #pragma unroll
  for (int r = 0; r < 16; r++){
    uint64_t e = in[base + (size_t)r*64 + lane];
    elems[r] = e;
    unsigned d = (unsigned)((e >> shift) & 0xFF);
    uint64_t m = ~0ull;
    #pragma unroll
    for (int b = 0; b < 8; b++){
      uint64_t bb = __ballot((d >> b) & 1u);
      m &= ((d >> b) & 1u) ? bb : ~bb;
    }
    unsigned rr   = (unsigned)__popcll(m & ltm);
    unsigned prev = wrun[w*256 + d];
    __builtin_amdgcn_wave_barrier();
    if (rr == 0) wrun[w*256 + d] = prev + (unsigned)__popcll(m);
    __builtin_amdgcn_wave_barrier();
    rnk[r] = prev + rr;
    dg[r]  = d;
  }
  __syncthreads();
  {
    unsigned d = t;
    unsigned c0 = wrun[d], c1 = wrun[256+d], c2 = wrun[512+d], c3 = wrun[768+d];
    unsigned cnt = c0 + c1 + c2 + c3;
    unsigned tot;
    unsigned ldig  = blockScanExcl(cnt, t, lw, &tot);       // local digit start
    unsigned tot2;
    unsigned dbase = blockScanExcl(dtot[d], t, lw, &tot2);  // global digit base
    gput[d] = dbase + gh[d * NTILES + blockIdx.x] - ldig;
    wrun[d]       = ldig;
    wrun[256 + d] = ldig + c0;
    wrun[512 + d] = ldig + c0 + c1;
    wrun[768 + d] = ldig + c0 + c1 + c2;
  }
  __syncthreads();
  #pragma unroll
  for (int r = 0; r < 16; r++)
    stage[ wrun[w*256 + dg[r]] + rnk[r] ] = elems[r];
  __syncthreads();
  #pragma unroll
  for (int r = 0; r < 16; r++){
    unsigned j = (unsigned)r * 256u + t;
    uint64_t e = stage[j];
    unsigned d = (unsigned)((e >> shift) & 0xFF);
    unsigned dest = gput[d] + j;
    if (FINAL){
      if (dest < R_N){
        uint32_t key = (uint32_t)(e >> 32);
        fout[2u*dest]        = (float)(key >> 12);
        fout[2u*dest + 1u]   = (float)(key & 4095u);
        fout[2u*R_N + dest]  = __uint_as_float(~(uint32_t)e);
      }
    } else {
      out[dest] = e;
    }
  }
}

__global__ __launch_bounds__(256) void k_scatter(const uint64_t* __restrict__ in,
                                                 uint64_t* __restrict__ out,
                                                 unsigned shift,
                                                 const unsigned* __restrict__ gh,
                                                 const unsigned* __restrict__ dtot){
  scatter_body<false>(in, out, nullptr, shift, gh, dtot);
}

__global__ __launch_bounds__(256) void k_scatter_out(const uint64_t* __restrict__ in,
                                                     float* __restrict__ fout,
                                                     unsigned shift,
                                                     const unsigned* __restrict__ gh,
                                                     const unsigned* __restrict__ dtot){
  scatter_body<true>(in, nullptr, fout, shift, gh, dtot);
}

// Count real segment heads per 256-elem block (phantom pad-head excluded so
// the scanned total is the exact candidate count U).
__global__ __launch_bounds__(256) void k_headcount(const uint64_t* __restrict__ in,
                                                   unsigned* __restrict__ hcnt){
  __shared__ unsigned wc[4];
  unsigned t = threadIdx.x, lane = t & 63u, w = t >> 6;
  size_t p = (size_t)blockIdx.x * 256 + t;
  uint64_t e = in[p];
  uint32_t k = (uint32_t)(e >> 32);
  bool head = ((p == 0) || ((uint32_t)(in[p-1] >> 32) != k)) && ((uint32_t)e != PAD_VAL);
  uint64_t m = __ballot(head);
  if (lane == 0) wc[w] = (unsigned)__popcll(m);
  __syncthreads();
  if (t == 0) hcnt[blockIdx.x] = wc[0] + wc[1] + wc[2] + wc[3];
}

// Fast single-block scan of NSB head counts via u16 LDS staging; writes U.
__global__ __launch_bounds__(256) void k_scanheads(unsigned* __restrict__ hcnt,
                                                   unsigned* __restrict__ utot){
  __shared__ unsigned short buf[NSB];    // counts <= 256 fit u16; 34.4 KB
  __shared__ unsigned lw[4];
  unsigned t = threadIdx.x;
  for (unsigned i = t; i < NSB; i += 256) buf[i] = (unsigned short)hcnt[i];
  __syncthreads();
  const unsigned CH = (NSB + 255) / 256; // 68 elems/thread, blocked
  unsigned s = 0;
  for (unsigned k = 0; k < CH; k++){
    unsigned i = t * CH + k;
    if (i < NSB) s += buf[i];
  }
  unsigned tot;
  unsigned carry = blockScanExcl(s, t, lw, &tot);
  for (unsigned k = 0; k < CH; k++){
    unsigned i = t * CH + k;
    if (i < NSB){ unsigned v = buf[i]; hcnt[i] = carry; carry += v; }
  }
  if (t == 0) utot[0] = tot;
}

// Sentinel-fill only [U, NPAD) (sentinel sorts last in the value phase).
__global__ __launch_bounds__(256) void k_fill_tail(uint64_t* __restrict__ A,
                                                   const unsigned* __restrict__ utot){
  unsigned U = utot[0];
  unsigned i = blockIdx.x * 256u + threadIdx.x;
  if (i >= U) A[i] = ((uint64_t)PAD_KEY << 32) | (uint64_t)PAD_VAL;
}

// In-order segmented sum: head thread walks its key segment sequentially
// (original contribution order thanks to the stable key sort) -> fp32 sum is
// bit-identical to segment_sum. Candidates written dense, key-ascending.
__global__ __launch_bounds__(256) void k_segsum(const uint64_t* __restrict__ in,
                                                uint64_t* __restrict__ out,
                                                const unsigned* __restrict__ hbase){
  __shared__ unsigned wc[4], woffs[4];
  unsigned t = threadIdx.x, lane = t & 63u, w = t >> 6;
  size_t p = (size_t)blockIdx.x * 256 + t;
  uint64_t e0 = in[p];
  uint32_t k = (uint32_t)(e0 >> 32);
  bool head = ((p == 0) || ((uint32_t)(in[p-1] >> 32) != k)) && ((uint32_t)e0 != PAD_VAL);
  uint64_t m = __ballot(head);
  if (lane == 0) wc[w] = (unsigned)__popcll(m);
  __syncthreads();
  if (t == 0){ unsigned a = 0; for (int i = 0; i < 4; i++){ woffs[i] = a; a += wc[i]; } }
  __syncthreads();
  if (head){
    uint64_t ltm = (lane == 0) ? 0ull : (~0ull >> (64u - lane));
    unsigned rank = (unsigned)__popcll(m & ltm);
    unsigned oidx = hbase[blockIdx.x] + woffs[w] + rank;
    float s = __uint_as_float((uint32_t)e0);
    size_t q = p + 1;
    while (q < NPAD){
      uint64_t e = in[q];
      if ((uint32_t)(e >> 32) != k) break;
      uint32_t vb = (uint32_t)e;
      if (vb == PAD_VAL) break;
      s += __uint_as_float(vb);
      q++;
    }
    out[oidx] = ((uint64_t)k << 32) | (uint64_t)(uint32_t)(~__float_as_uint(s));
  }
}

extern "C" void kernel_launch(void* const* d_in, const int* in_sizes, int n_in,
                              void* d_out, int out_size, void* d_ws, size_t ws_size,
                              hipStream_t stream) {
  const int*   sidx = (const int*)d_in[0];
  const int*   ridx = (const int*)d_in[1];
  const float* rval = (const float*)d_in[2];
  const float* grad = (const float*)d_in[3];
  float* out = (float*)d_out;

  uint64_t* A0   = (uint64_t*)d_ws;                       // 35.3 MB
  uint64_t* A1   = A0 + NPAD;                             // 35.3 MB
  unsigned* gh   = (unsigned*)(A1 + NPAD);                // 1.1 MB
  unsigned* dtot = gh + 256 * NTILES;                     // 1 KB
  unsigned* hcnt = dtot + 256;                            // 67 KB
  unsigned* utot = hcnt + NSB;                            // 4 B

  k_build<<<NSB, 256, 0, stream>>>(sidx, ridx, rval, grad, A0);

  // Stable key sort: 24 bits, 3 x 8-bit passes. A0->A1->A0->A1.
  k_hist    <<<NTILES, 256, 0, stream>>>(A0, 32, gh);
  k_scanrows<<<256,    256, 0, stream>>>(gh, dtot);
  k_scatter <<<NTILES, 256, 0, stream>>>(A0, A1, 32, gh, dtot);
  k_hist    <<<NTILES, 256, 0, stream>>>(A1, 40, gh);
  k_scanrows<<<256,    256, 0, stream>>>(gh, dtot);
  k_scatter <<<NTILES, 256, 0, stream>>>(A1, A0, 40, gh, dtot);
  k_hist    <<<NTILES, 256, 0, stream>>>(A0, 48, gh);
  k_scanrows<<<256,    256, 0, stream>>>(gh, dtot);
  k_scatter <<<NTILES, 256, 0, stream>>>(A0, A1, 48, gh, dtot);

  // Coalesce.
  k_headcount<<<NSB, 256, 0, stream>>>(A1, hcnt);
  k_scanheads<<<1,   256, 0, stream>>>(hcnt, utot);
  k_fill_tail<<<NSB, 256, 0, stream>>>(A0, utot);
  k_segsum   <<<NSB, 256, 0, stream>>>(A1, A0, hcnt);

  // Stable value sort: 32 bits of ~vbits, 4 x 8-bit passes; final pass fused
  // with output emission. A0->A1->A0->A1->out.
  k_hist    <<<NTILES, 256, 0, stream>>>(A0, 0, gh);
  k_scanrows<<<256,    256, 0, stream>>>(gh, dtot);
  k_scatter <<<NTILES, 256, 0, stream>>>(A0, A1, 0, gh, dtot);
  k_hist    <<<NTILES, 256, 0, stream>>>(A1, 8, gh);
  k_scanrows<<<256,    256, 0, stream>>>(gh, dtot);
  k_scatter <<<NTILES, 256, 0, stream>>>(A1, A0, 8, gh, dtot);
  k_hist    <<<NTILES, 256, 0, stream>>>(A0, 16, gh);
  k_scanrows<<<256,    256, 0, stream>>>(gh, dtot);
  k_scatter <<<NTILES, 256, 0, stream>>>(A0, A1, 16, gh, dtot);
  k_hist       <<<NTILES, 256, 0, stream>>>(A1, 24, gh);
  k_scanrows   <<<256,    256, 0, stream>>>(gh, dtot);
  k_scatter_out<<<NTILES, 256, 0, stream>>>(A1, out, 24, gh, dtot);
}